// Round 5
// baseline (395.200 us; speedup 1.0000x reference)
//
#include <hip/hip_runtime.h>

// Problem constants (fixed by setup_inputs in the reference)
constexpr int BS    = 2;
constexpr int A     = 900;
constexpr int P     = 13;
constexpr int NCAM  = 6;
constexpr int NLVL  = 4;
constexpr int NGRP  = 8;
constexpr int C     = 256;
constexpr int K     = 89760;                 // sum of H*W over 6 cams x 4 levels
constexpr int NSAMP = P * NCAM * NLVL;       // 312 (p, cam, lvl) combos
constexpr int NCORN = NSAMP * 4;             // 1248 bilinear corners
constexpr int AWN   = NSAMP * NGRP;          // 2496 attention weights per (b,a)
constexpr int SPW   = NSAMP / 4;             // 78 samples per wave
constexpr int PAIRS = SPW / 2;               // 39 sample-pairs per wave
constexpr size_t NVAL = (size_t)BS * K * C;  // 45,957,120 elements
constexpr int NC8  = (int)(NVAL / 8);        // 5,744,640 8-element chunks

typedef unsigned short us8 __attribute__((ext_vector_type(8)));

__device__ __forceinline__ float bf2f(unsigned short h) {
    unsigned int u = ((unsigned int)h) << 16;
    return __builtin_bit_cast(float, u);
}
__device__ __forceinline__ unsigned short f2bf(float f) {
    unsigned int u = __builtin_bit_cast(unsigned int, f);
    u = u + 0x7FFFu + ((u >> 16) & 1u);      // round-to-nearest-even
    return (unsigned short)(u >> 16);
}

// Shared device body: build per-(b,a) sample metadata into LDS
__device__ __forceinline__ void build_meta(
    int ba, int tid,
    const int* __restrict__ shapes, const int* __restrict__ starts,
    const float* __restrict__ locs,
    int* idx_s, float* wgt_s)
{
    for (int t = tid; t < NSAMP; t += 256) {
        const int p   = t / (NCAM * NLVL);
        const int rem = t - p * (NCAM * NLVL);
        const int cam = rem >> 2;      // NLVL == 4
        const int lvl = rem & 3;

        const size_t lbase = ((((size_t)ba) * P + p) * NCAM + cam) * 2;
        const float lx = locs[lbase + 0];
        const float ly = locs[lbase + 1];

        const int H  = shapes[(cam * NLVL + lvl) * 2 + 0];
        const int W  = shapes[(cam * NLVL + lvl) * 2 + 1];
        const int st = starts[cam * NLVL + lvl];

        const float x = lx * (float)W - 0.5f;
        const float y = ly * (float)H - 0.5f;
        const float x0f = floorf(x), y0f = floorf(y);
        const float dx = x - x0f,   dy = y - y0f;
        const int   x0 = (int)x0f,  y0 = (int)y0f;

#pragma unroll
        for (int corner = 0; corner < 4; ++corner) {
            const int oy = corner >> 1, ox = corner & 1;
            const int yi = y0 + oy, xi = x0 + ox;
            float w = (oy ? dy : 1.0f - dy) * (ox ? dx : 1.0f - dx);
            const bool valid = (yi >= 0) & (yi < H) & (xi >= 0) & (xi < W);
            if (!valid) w = 0.0f;
            const int yc = min(max(yi, 0), H - 1);
            const int xc = min(max(xi, 0), W - 1);
            idx_s[t * 4 + corner] = st + yc * W + xc;
            wgt_s[t * 4 + corner] = w;
        }
    }
}

// ---- Producer: fp32 -> bf16 into workspace, write-through + release ----
__global__ __launch_bounds__(256) void cvt_kernel(
    const float* __restrict__ in, us8* __restrict__ out, int n8)
{
    const int stride = gridDim.x * 256;
    for (int i = blockIdx.x * 256 + threadIdx.x; i < n8; i += stride) {
        const float4 a = reinterpret_cast<const float4*>(in)[2 * i + 0];
        const float4 b = reinterpret_cast<const float4*>(in)[2 * i + 1];
        us8 r;
        r[0] = f2bf(a.x); r[1] = f2bf(a.y); r[2] = f2bf(a.z); r[3] = f2bf(a.w);
        r[4] = f2bf(b.x); r[5] = f2bf(b.y); r[6] = f2bf(b.z); r[7] = f2bf(b.w);
        __builtin_nontemporal_store(r, out + i);
    }
    // Release at agent scope: write back this XCD's dirty L2 lines so the
    // consumer kernel (any XCD) sees them via the LLC. Graph replay skips
    // the runtime's inter-dispatch cache maintenance (R3 failure).
    __builtin_amdgcn_fence(__ATOMIC_RELEASE, "agent");
}

// ---- Consumer: bf16 gather, 2 samples per wave, ushort8 per lane ----
__global__ __launch_bounds__(256, 8) void dfa_bf16(
    const unsigned short* __restrict__ vbf,  // [BS][K][C] bf16
    const int*   __restrict__ shapes,
    const int*   __restrict__ starts,
    const float* __restrict__ locs,
    const float* __restrict__ aw,
    float*       __restrict__ out)
{
    __shared__ int   idx_s[NCORN];
    __shared__ float wgt_s[NCORN];
    __shared__ float red_s[3][32][8];

    const int tid = threadIdx.x;

    // Acquire at agent scope (wave 0 only; covers this XCD's L2): drop any
    // stale lines so vbf reads come from the LLC the producer released to.
    if (tid < 64) __builtin_amdgcn_fence(__ATOMIC_ACQUIRE, "agent");

    const int ba = blockIdx.x;
    const int b  = ba / A;

    build_meta(ba, tid, shapes, starts, locs, idx_s, wgt_s);
    __syncthreads();   // also orders the acquire fence before all vbf reads

    const int wid  = tid >> 6;         // wave id 0..3
    const int lane = tid & 63;
    const int half = lane >> 5;        // which sample of the pair
    const int cl   = lane & 31;        // channel-lane: channels [cl*8, cl*8+8)
    const int g    = cl >> 2;          // group = (cl*8)/32

    const unsigned short* __restrict__ vbase =
        vbf + (size_t)b * (size_t)K * C + (size_t)cl * 8;
    const float* __restrict__ awp = aw + (size_t)ba * AWN;

    float acc[8] = {0.f, 0.f, 0.f, 0.f, 0.f, 0.f, 0.f, 0.f};

    const int sbase = wid * SPW + half;
    for (int t = 0; t < PAIRS; ++t) {
        const int s  = sbase + 2 * t;
        const float w0 = wgt_s[s * 4 + 0];
        const float w1 = wgt_s[s * 4 + 1];
        const float w2 = wgt_s[s * 4 + 2];
        const float w3 = wgt_s[s * 4 + 3];
        const int   i0 = idx_s[s * 4 + 0];
        const int   i1 = idx_s[s * 4 + 1];
        const int   i2 = idx_s[s * 4 + 2];
        const int   i3 = idx_s[s * 4 + 3];

        const us8 u0 = *reinterpret_cast<const us8*>(vbase + (size_t)i0 * C);
        const us8 u1 = *reinterpret_cast<const us8*>(vbase + (size_t)i1 * C);
        const us8 u2 = *reinterpret_cast<const us8*>(vbase + (size_t)i2 * C);
        const us8 u3 = *reinterpret_cast<const us8*>(vbase + (size_t)i3 * C);

        const float wa = awp[s * NGRP + g];

#pragma unroll
        for (int j = 0; j < 8; ++j) {
            float v = w0 * bf2f(u0[j]);
            v = fmaf(w1, bf2f(u1[j]), v);
            v = fmaf(w2, bf2f(u2[j]), v);
            v = fmaf(w3, bf2f(u3[j]), v);
            acc[j] = fmaf(v, wa, acc[j]);
        }
    }

    // combine the two half-wave partials (same channels, different samples)
#pragma unroll
    for (int j = 0; j < 8; ++j) acc[j] += __shfl_xor(acc[j], 32, 64);

    if (wid > 0 && lane < 32) {
#pragma unroll
        for (int j = 0; j < 8; ++j) red_s[wid - 1][cl][j] = acc[j];
    }
    __syncthreads();

    if (wid == 0 && lane < 32) {
#pragma unroll
        for (int j = 0; j < 8; ++j)
            acc[j] += red_s[0][cl][j] + red_s[1][cl][j] + red_s[2][cl][j];
        float4 o0 = {acc[0], acc[1], acc[2], acc[3]};
        float4 o1 = {acc[4], acc[5], acc[6], acc[7]};
        float4* op = reinterpret_cast<float4*>(out + (size_t)ba * C + cl * 8);
        op[0] = o0;
        op[1] = o1;
    }
}

// ---- Fallback: proven fp32 single kernel (no workspace dependency) ----
__global__ __launch_bounds__(256, 8) void dfa_f32(
    const float* __restrict__ value,
    const int*   __restrict__ shapes,
    const int*   __restrict__ starts,
    const float* __restrict__ locs,
    const float* __restrict__ aw,
    float*       __restrict__ out)
{
    __shared__ int    idx_s[NCORN];
    __shared__ float  wgt_s[NCORN];
    __shared__ float4 red_s[3][64];

    const int ba  = blockIdx.x;
    const int tid = threadIdx.x;
    const int b   = ba / A;

    build_meta(ba, tid, shapes, starts, locs, idx_s, wgt_s);
    __syncthreads();

    const int wid  = tid >> 6;
    const int lane = tid & 63;
    const int g    = lane >> 3;

    const float* __restrict__ awp = aw + (size_t)ba * AWN;
    const float* __restrict__ vbase = value + (size_t)b * K * C + lane * 4;

    float4 acc = {0.0f, 0.0f, 0.0f, 0.0f};
    const int s_end = (wid + 1) * SPW;
#pragma unroll 2
    for (int s = wid * SPW; s < s_end; ++s) {
        const float w0 = wgt_s[s * 4 + 0];
        const float w1 = wgt_s[s * 4 + 1];
        const float w2 = wgt_s[s * 4 + 2];
        const float w3 = wgt_s[s * 4 + 3];
        const int   i0 = idx_s[s * 4 + 0];
        const int   i1 = idx_s[s * 4 + 1];
        const int   i2 = idx_s[s * 4 + 2];
        const int   i3 = idx_s[s * 4 + 3];

        const float4 v0 = *reinterpret_cast<const float4*>(vbase + (size_t)i0 * C);
        const float4 v1 = *reinterpret_cast<const float4*>(vbase + (size_t)i1 * C);
        const float4 v2 = *reinterpret_cast<const float4*>(vbase + (size_t)i2 * C);
        const float4 v3 = *reinterpret_cast<const float4*>(vbase + (size_t)i3 * C);

        const float wa = awp[s * NGRP + g];

        float4 t;
        t.x = w0 * v0.x; t.y = w0 * v0.y; t.z = w0 * v0.z; t.w = w0 * v0.w;
        t.x = fmaf(w1, v1.x, t.x); t.y = fmaf(w1, v1.y, t.y);
        t.z = fmaf(w1, v1.z, t.z); t.w = fmaf(w1, v1.w, t.w);
        t.x = fmaf(w2, v2.x, t.x); t.y = fmaf(w2, v2.y, t.y);
        t.z = fmaf(w2, v2.z, t.z); t.w = fmaf(w2, v2.w, t.w);
        t.x = fmaf(w3, v3.x, t.x); t.y = fmaf(w3, v3.y, t.y);
        t.z = fmaf(w3, v3.z, t.z); t.w = fmaf(w3, v3.w, t.w);

        acc.x = fmaf(t.x, wa, acc.x);
        acc.y = fmaf(t.y, wa, acc.y);
        acc.z = fmaf(t.z, wa, acc.z);
        acc.w = fmaf(t.w, wa, acc.w);
    }

    if (wid > 0) red_s[wid - 1][lane] = acc;
    __syncthreads();

    if (wid == 0) {
        const float4 r0 = red_s[0][lane];
        const float4 r1 = red_s[1][lane];
        const float4 r2 = red_s[2][lane];
        acc.x += r0.x + r1.x + r2.x;
        acc.y += r0.y + r1.y + r2.y;
        acc.z += r0.z + r1.z + r2.z;
        acc.w += r0.w + r1.w + r2.w;
        *reinterpret_cast<float4*>(out + (size_t)ba * C + lane * 4) = acc;
    }
}

extern "C" void kernel_launch(void* const* d_in, const int* in_sizes, int n_in,
                              void* d_out, int out_size, void* d_ws, size_t ws_size,
                              hipStream_t stream) {
    const float* value  = (const float*)d_in[0];
    const int*   shapes = (const int*)d_in[1];
    const int*   starts = (const int*)d_in[2];
    const float* locs   = (const float*)d_in[3];
    const float* aw     = (const float*)d_in[4];
    float*       out    = (float*)d_out;

    const size_t bf16_bytes = NVAL * sizeof(unsigned short);

    if (ws_size >= bf16_bytes) {
        us8* vbf = (us8*)d_ws;
        cvt_kernel<<<dim3(2048), dim3(256), 0, stream>>>(value, vbf, NC8);
        dfa_bf16<<<dim3(BS * A), dim3(256), 0, stream>>>(
            (const unsigned short*)d_ws, shapes, starts, locs, aw, out);
    } else {
        dfa_f32<<<dim3(BS * A), dim3(256), 0, stream>>>(
            value, shapes, starts, locs, aw, out);
    }
}

// Round 6
// 199.120 us; speedup vs baseline: 1.9847x; 1.9847x over previous
//
#include <hip/hip_runtime.h>

// Problem constants (fixed by setup_inputs in the reference)
constexpr int BS    = 2;
constexpr int A     = 900;
constexpr int P     = 13;
constexpr int NCAM  = 6;
constexpr int NLVL  = 4;
constexpr int NGRP  = 8;
constexpr int C     = 256;
constexpr int K     = 89760;                 // sum of H*W over 6 cams x 4 levels
constexpr int NSAMP = P * NCAM * NLVL;       // 312 (p, cam, lvl) combos
constexpr int NCORN = NSAMP * 4;             // 1248 bilinear corners
constexpr int AWN   = NSAMP * NGRP;          // 2496 attention weights per (b,a)
constexpr int SPW   = NSAMP / 4;             // 78 samples per wave
constexpr int PAIRS = SPW / 2;               // 39 sample-pairs per wave
constexpr size_t NVAL = (size_t)BS * K * C;  // 45,957,120 elements
constexpr int NC8  = (int)(NVAL / 8);        // 5,744,640 8-element chunks

typedef unsigned short us8 __attribute__((ext_vector_type(8)));

__device__ __forceinline__ float bf2f(unsigned short h) {
    unsigned int u = ((unsigned int)h) << 16;
    return __builtin_bit_cast(float, u);
}
__device__ __forceinline__ unsigned short f2bf(float f) {
    unsigned int u = __builtin_bit_cast(unsigned int, f);
    u = u + 0x7FFFu + ((u >> 16) & 1u);      // round-to-nearest-even
    return (unsigned short)(u >> 16);
}

// Shared device body: build per-(b,a) sample metadata into LDS
__device__ __forceinline__ void build_meta(
    int ba, int tid,
    const int* __restrict__ shapes, const int* __restrict__ starts,
    const float* __restrict__ locs,
    int* idx_s, float* wgt_s)
{
    for (int t = tid; t < NSAMP; t += 256) {
        const int p   = t / (NCAM * NLVL);
        const int rem = t - p * (NCAM * NLVL);
        const int cam = rem >> 2;      // NLVL == 4
        const int lvl = rem & 3;

        const size_t lbase = ((((size_t)ba) * P + p) * NCAM + cam) * 2;
        const float lx = locs[lbase + 0];
        const float ly = locs[lbase + 1];

        const int H  = shapes[(cam * NLVL + lvl) * 2 + 0];
        const int W  = shapes[(cam * NLVL + lvl) * 2 + 1];
        const int st = starts[cam * NLVL + lvl];

        const float x = lx * (float)W - 0.5f;
        const float y = ly * (float)H - 0.5f;
        const float x0f = floorf(x), y0f = floorf(y);
        const float dx = x - x0f,   dy = y - y0f;
        const int   x0 = (int)x0f,  y0 = (int)y0f;

#pragma unroll
        for (int corner = 0; corner < 4; ++corner) {
            const int oy = corner >> 1, ox = corner & 1;
            const int yi = y0 + oy, xi = x0 + ox;
            float w = (oy ? dy : 1.0f - dy) * (ox ? dx : 1.0f - dx);
            const bool valid = (yi >= 0) & (yi < H) & (xi >= 0) & (xi < W);
            if (!valid) w = 0.0f;
            const int yc = min(max(yi, 0), H - 1);
            const int xc = min(max(xi, 0), W - 1);
            idx_s[t * 4 + corner] = st + yc * W + xc;
            wgt_s[t * 4 + corner] = w;
        }
    }
}

// ---- Producer: fp32 -> bf16 into workspace via agent-scope stores ----
// Agent-scope relaxed atomic stores emit sc1 (write-through past the
// non-coherent per-XCD L2 to the device coherence point) per store —
// no bulk buffer_wbl2 needed (R5's per-wave release fence cost ~330us).
__global__ __launch_bounds__(256) void cvt_kernel(
    const float* __restrict__ in, unsigned long long* __restrict__ out, int n8)
{
    const int stride = gridDim.x * 256;
    for (int i = blockIdx.x * 256 + threadIdx.x; i < n8; i += stride) {
        const float4 a = reinterpret_cast<const float4*>(in)[2 * i + 0];
        const float4 b = reinterpret_cast<const float4*>(in)[2 * i + 1];
        us8 r;
        r[0] = f2bf(a.x); r[1] = f2bf(a.y); r[2] = f2bf(a.z); r[3] = f2bf(a.w);
        r[4] = f2bf(b.x); r[5] = f2bf(b.y); r[6] = f2bf(b.z); r[7] = f2bf(b.w);
        const unsigned long long* p = reinterpret_cast<const unsigned long long*>(&r);
        __hip_atomic_store(&out[2 * i + 0], p[0], __ATOMIC_RELAXED, __HIP_MEMORY_SCOPE_AGENT);
        __hip_atomic_store(&out[2 * i + 1], p[1], __ATOMIC_RELAXED, __HIP_MEMORY_SCOPE_AGENT);
    }
}

// ---- Consumer: bf16 gather, 2 samples per wave, ushort8 per lane ----
__global__ __launch_bounds__(256, 8) void dfa_bf16(
    const unsigned short* __restrict__ vbf,  // [BS][K][C] bf16
    const int*   __restrict__ shapes,
    const int*   __restrict__ starts,
    const float* __restrict__ locs,
    const float* __restrict__ aw,
    float*       __restrict__ out)
{
    __shared__ int   idx_s[NCORN];
    __shared__ float wgt_s[NCORN];
    __shared__ float red_s[3][32][8];

    const int tid = threadIdx.x;

    // Acquire at agent scope (wave 0 only; buffer_inv drops stale clean
    // lines in this XCD's L2 so vbf reads see the producer's sc1 writes).
    if (tid < 64) __builtin_amdgcn_fence(__ATOMIC_ACQUIRE, "agent");

    const int ba = blockIdx.x;
    const int b  = ba / A;

    build_meta(ba, tid, shapes, starts, locs, idx_s, wgt_s);
    __syncthreads();   // also orders the acquire fence before all vbf reads

    const int wid  = tid >> 6;         // wave id 0..3
    const int lane = tid & 63;
    const int half = lane >> 5;        // which sample of the pair
    const int cl   = lane & 31;        // channel-lane: channels [cl*8, cl*8+8)
    const int g    = cl >> 2;          // group = (cl*8)/32

    const unsigned short* __restrict__ vbase =
        vbf + (size_t)b * (size_t)K * C + (size_t)cl * 8;
    const float* __restrict__ awp = aw + (size_t)ba * AWN;

    float acc[8] = {0.f, 0.f, 0.f, 0.f, 0.f, 0.f, 0.f, 0.f};

    const int sbase = wid * SPW + half;
    for (int t = 0; t < PAIRS; ++t) {
        const int s  = sbase + 2 * t;
        const float w0 = wgt_s[s * 4 + 0];
        const float w1 = wgt_s[s * 4 + 1];
        const float w2 = wgt_s[s * 4 + 2];
        const float w3 = wgt_s[s * 4 + 3];
        const int   i0 = idx_s[s * 4 + 0];
        const int   i1 = idx_s[s * 4 + 1];
        const int   i2 = idx_s[s * 4 + 2];
        const int   i3 = idx_s[s * 4 + 3];

        const us8 u0 = *reinterpret_cast<const us8*>(vbase + (size_t)i0 * C);
        const us8 u1 = *reinterpret_cast<const us8*>(vbase + (size_t)i1 * C);
        const us8 u2 = *reinterpret_cast<const us8*>(vbase + (size_t)i2 * C);
        const us8 u3 = *reinterpret_cast<const us8*>(vbase + (size_t)i3 * C);

        const float wa = awp[s * NGRP + g];

#pragma unroll
        for (int j = 0; j < 8; ++j) {
            float v = w0 * bf2f(u0[j]);
            v = fmaf(w1, bf2f(u1[j]), v);
            v = fmaf(w2, bf2f(u2[j]), v);
            v = fmaf(w3, bf2f(u3[j]), v);
            acc[j] = fmaf(v, wa, acc[j]);
        }
    }

    // combine the two half-wave partials (same channels, different samples)
#pragma unroll
    for (int j = 0; j < 8; ++j) acc[j] += __shfl_xor(acc[j], 32, 64);

    if (wid > 0 && lane < 32) {
#pragma unroll
        for (int j = 0; j < 8; ++j) red_s[wid - 1][cl][j] = acc[j];
    }
    __syncthreads();

    if (wid == 0 && lane < 32) {
#pragma unroll
        for (int j = 0; j < 8; ++j)
            acc[j] += red_s[0][cl][j] + red_s[1][cl][j] + red_s[2][cl][j];
        float4 o0 = {acc[0], acc[1], acc[2], acc[3]};
        float4 o1 = {acc[4], acc[5], acc[6], acc[7]};
        float4* op = reinterpret_cast<float4*>(out + (size_t)ba * C + cl * 8);
        op[0] = o0;
        op[1] = o1;
    }
}

// ---- Fallback: proven fp32 single kernel (no workspace dependency) ----
__global__ __launch_bounds__(256, 8) void dfa_f32(
    const float* __restrict__ value,
    const int*   __restrict__ shapes,
    const int*   __restrict__ starts,
    const float* __restrict__ locs,
    const float* __restrict__ aw,
    float*       __restrict__ out)
{
    __shared__ int    idx_s[NCORN];
    __shared__ float  wgt_s[NCORN];
    __shared__ float4 red_s[3][64];

    const int ba  = blockIdx.x;
    const int tid = threadIdx.x;
    const int b   = ba / A;

    build_meta(ba, tid, shapes, starts, locs, idx_s, wgt_s);
    __syncthreads();

    const int wid  = tid >> 6;
    const int lane = tid & 63;
    const int g    = lane >> 3;

    const float* __restrict__ awp = aw + (size_t)ba * AWN;
    const float* __restrict__ vbase = value + (size_t)b * K * C + lane * 4;

    float4 acc = {0.0f, 0.0f, 0.0f, 0.0f};
    const int s_end = (wid + 1) * SPW;
#pragma unroll 2
    for (int s = wid * SPW; s < s_end; ++s) {
        const float w0 = wgt_s[s * 4 + 0];
        const float w1 = wgt_s[s * 4 + 1];
        const float w2 = wgt_s[s * 4 + 2];
        const float w3 = wgt_s[s * 4 + 3];
        const int   i0 = idx_s[s * 4 + 0];
        const int   i1 = idx_s[s * 4 + 1];
        const int   i2 = idx_s[s * 4 + 2];
        const int   i3 = idx_s[s * 4 + 3];

        const float4 v0 = *reinterpret_cast<const float4*>(vbase + (size_t)i0 * C);
        const float4 v1 = *reinterpret_cast<const float4*>(vbase + (size_t)i1 * C);
        const float4 v2 = *reinterpret_cast<const float4*>(vbase + (size_t)i2 * C);
        const float4 v3 = *reinterpret_cast<const float4*>(vbase + (size_t)i3 * C);

        const float wa = awp[s * NGRP + g];

        float4 t;
        t.x = w0 * v0.x; t.y = w0 * v0.y; t.z = w0 * v0.z; t.w = w0 * v0.w;
        t.x = fmaf(w1, v1.x, t.x); t.y = fmaf(w1, v1.y, t.y);
        t.z = fmaf(w1, v1.z, t.z); t.w = fmaf(w1, v1.w, t.w);
        t.x = fmaf(w2, v2.x, t.x); t.y = fmaf(w2, v2.y, t.y);
        t.z = fmaf(w2, v2.z, t.z); t.w = fmaf(w2, v2.w, t.w);
        t.x = fmaf(w3, v3.x, t.x); t.y = fmaf(w3, v3.y, t.y);
        t.z = fmaf(w3, v3.z, t.z); t.w = fmaf(w3, v3.w, t.w);

        acc.x = fmaf(t.x, wa, acc.x);
        acc.y = fmaf(t.y, wa, acc.y);
        acc.z = fmaf(t.z, wa, acc.z);
        acc.w = fmaf(t.w, wa, acc.w);
    }

    if (wid > 0) red_s[wid - 1][lane] = acc;
    __syncthreads();

    if (wid == 0) {
        const float4 r0 = red_s[0][lane];
        const float4 r1 = red_s[1][lane];
        const float4 r2 = red_s[2][lane];
        acc.x += r0.x + r1.x + r2.x;
        acc.y += r0.y + r1.y + r2.y;
        acc.z += r0.z + r1.z + r2.z;
        acc.w += r0.w + r1.w + r2.w;
        *reinterpret_cast<float4*>(out + (size_t)ba * C + lane * 4) = acc;
    }
}

extern "C" void kernel_launch(void* const* d_in, const int* in_sizes, int n_in,
                              void* d_out, int out_size, void* d_ws, size_t ws_size,
                              hipStream_t stream) {
    const float* value  = (const float*)d_in[0];
    const int*   shapes = (const int*)d_in[1];
    const int*   starts = (const int*)d_in[2];
    const float* locs   = (const float*)d_in[3];
    const float* aw     = (const float*)d_in[4];
    float*       out    = (float*)d_out;

    const size_t bf16_bytes = NVAL * sizeof(unsigned short);

    if (ws_size >= bf16_bytes) {
        cvt_kernel<<<dim3(2048), dim3(256), 0, stream>>>(
            value, (unsigned long long*)d_ws, NC8);
        dfa_bf16<<<dim3(BS * A), dim3(256), 0, stream>>>(
            (const unsigned short*)d_ws, shapes, starts, locs, aw, out);
    } else {
        dfa_f32<<<dim3(BS * A), dim3(256), 0, stream>>>(
            value, shapes, starts, locs, aw, out);
    }
}